// Round 18
// baseline (55.400 us; speedup 1.0000x reference)
//
#include <hip/hip_runtime.h>

// MSMLTransformerLayer — R17 bodies, repacked DAG: act (independent until
// attlin) moves from launch 1 into launch 2, co-resident with kq so the two
// GEMM populations fill each other's stalls (m114 overlap). L1: h + casts.

#define DIM 256
#define NTOK 4096

typedef __attribute__((ext_vector_type(8))) short short8;
typedef __attribute__((ext_vector_type(4))) short short4v;
typedef __attribute__((ext_vector_type(4))) float f32x4;

__device__ __forceinline__ float silu_f(float z) { return z / (1.f + __expf(-z)); }
__device__ __forceinline__ float elu2_f(float z) { return z > 0.f ? z + 2.f : __expf(z) + 1.f; }

__device__ __forceinline__ short f2bf(float f) {
    union { float f; unsigned u; } v; v.f = f;
    unsigned r = v.u + 0x7fffu + ((v.u >> 16) & 1u);
    return (short)(r >> 16);
}
__device__ __forceinline__ float bf2f(short s) {
    union { unsigned u; float f; } v; v.u = ((unsigned)(unsigned short)s) << 16;
    return v.f;
}
__device__ __forceinline__ short8 cvt8(const float* src) {
    const float4 a = *(const float4*)src;
    const float4 c = *(const float4*)(src + 4);
    short8 s;
    s[0] = f2bf(a.x); s[1] = f2bf(a.y); s[2] = f2bf(a.z); s[3] = f2bf(a.w);
    s[4] = f2bf(c.x); s[5] = f2bf(c.y); s[6] = f2bf(c.z); s[7] = f2bf(c.w);
    return s;
}
__device__ __forceinline__ void cast_chunk(const float* __restrict__ src, short* __restrict__ dst,
                                           int chunk, int tid) {
    const int base = chunk * 8192 + tid * 32;
    #pragma unroll
    for (int j = 0; j < 4; ++j)
        *(short8*)(dst + base + j * 8) = cvt8(src + base + j * 8);
}

// ---------------- L1: h GEMM (LN in-kernel, silu) + Wk/Wq/Wl casts -----------
// grid (88,4): bx<64 GEMM tile 128x64 (dbuf+prefetch); bx in [64,88) casts.
__global__ __launch_bounds__(256) void gemm_h(
        const float* __restrict__ XF,
        const float* __restrict__ Wcf, const float* __restrict__ bc, short* __restrict__ H,
        const float* __restrict__ G, const float* __restrict__ Bt,
        const float* __restrict__ Wkf, short* __restrict__ WKB,
        const float* __restrict__ Wqf, short* __restrict__ WQB,
        const float* __restrict__ Wlf, short* __restrict__ WLB) {
    const int tid = threadIdx.x;
    if (blockIdx.x >= 64) {
        if (blockIdx.y == 0) {
            const int which = blockIdx.x - 64;
            if (which < 8) cast_chunk(Wkf, WKB, which, tid);
            else if (which < 16) cast_chunk(Wqf, WQB, which - 8, tid);
            else cast_chunk(Wlf, WLB, which - 16, tid);
        }
        return;
    }
    __shared__ __align__(16) short Xs[2][128 * 72];
    __shared__ __align__(16) short Ws[2][64 * 72];
    __shared__ float stats[128][2];
    const int wv = tid >> 6, l = tid & 63;
    const int lr = l & 15, lk = l >> 4;
    const int r0 = blockIdx.x * 128, c0 = blockIdx.y * 64;
    const int wm = (wv >> 1) * 64, wn = (wv & 1) * 32;
    const int sr = tid >> 3, sc = (tid & 7) * 8;

    {
        const int prow = tid >> 1, phalf = tid & 1;
        const float* src = XF + (size_t)(r0 + prow) * DIM + phalf * 128;
        float a1 = 0.f, a2 = 0.f;
        #pragma unroll 8
        for (int j = 0; j < 32; ++j) {
            const float4 v = *(const float4*)(src + j * 4);
            a1 += v.x + v.y + v.z + v.w;
            a2 += v.x * v.x + v.y * v.y + v.z * v.z + v.w * v.w;
        }
        a1 += __shfl_xor(a1, 1);
        a2 += __shfl_xor(a2, 1);
        if (!phalf) {
            const float mm = a1 * (1.f / DIM);
            stats[prow][0] = mm;
            stats[prow][1] = rsqrtf(a2 * (1.f / DIM) - mm * mm + 1e-5f);
        }
        __syncthreads();
    }

    f32x4 acc[4][2];
    #pragma unroll
    for (int i = 0; i < 4; ++i)
        #pragma unroll
        for (int j = 0; j < 2; ++j) acc[i][j] = (f32x4){0.f, 0.f, 0.f, 0.f};

    float4 xa[4][2], wa[2][2];
    #pragma unroll
    for (int p = 0; p < 4; ++p) {
        const float* src = XF + (size_t)(r0 + sr + p * 32) * DIM + sc;
        xa[p][0] = *(const float4*)src;
        xa[p][1] = *(const float4*)(src + 4);
    }
    #pragma unroll
    for (int p = 0; p < 2; ++p) {
        const float* src = Wcf + (size_t)(c0 + sr + p * 32) * DIM + sc;
        wa[p][0] = *(const float4*)src;
        wa[p][1] = *(const float4*)(src + 4);
    }

    int buf = 0;
    for (int s = 0; s < 4; ++s) {
        const int kt = s * 64;
        {
            const float4 g1 = *(const float4*)(G + kt + sc);
            const float4 g2 = *(const float4*)(G + kt + sc + 4);
            const float4 t1 = *(const float4*)(Bt + kt + sc);
            const float4 t2 = *(const float4*)(Bt + kt + sc + 4);
            const float gv[8] = {g1.x, g1.y, g1.z, g1.w, g2.x, g2.y, g2.z, g2.w};
            const float bv[8] = {t1.x, t1.y, t1.z, t1.w, t2.x, t2.y, t2.z, t2.w};
            #pragma unroll
            for (int p = 0; p < 4; ++p) {
                const int row = sr + p * 32;
                const float mm = stats[row][0], rs = stats[row][1];
                const float v[8] = {xa[p][0].x, xa[p][0].y, xa[p][0].z, xa[p][0].w,
                                    xa[p][1].x, xa[p][1].y, xa[p][1].z, xa[p][1].w};
                short8 sS;
                #pragma unroll
                for (int j = 0; j < 8; ++j) sS[j] = f2bf((v[j] - mm) * rs * gv[j] + bv[j]);
                *(short8*)&Xs[buf][row * 72 + sc] = sS;
            }
        }
        #pragma unroll
        for (int p = 0; p < 2; ++p) {
            const int row = sr + p * 32;
            const float v[8] = {wa[p][0].x, wa[p][0].y, wa[p][0].z, wa[p][0].w,
                                wa[p][1].x, wa[p][1].y, wa[p][1].z, wa[p][1].w};
            short8 sS;
            #pragma unroll
            for (int j = 0; j < 8; ++j) sS[j] = f2bf(v[j]);
            *(short8*)&Ws[buf][row * 72 + sc] = sS;
        }
        __syncthreads();
        if (s < 3) {
            const int ktn = kt + 64;
            #pragma unroll
            for (int p = 0; p < 4; ++p) {
                const float* src = XF + (size_t)(r0 + sr + p * 32) * DIM + ktn + sc;
                xa[p][0] = *(const float4*)src;
                xa[p][1] = *(const float4*)(src + 4);
            }
            #pragma unroll
            for (int p = 0; p < 2; ++p) {
                const float* src = Wcf + (size_t)(c0 + sr + p * 32) * DIM + ktn + sc;
                wa[p][0] = *(const float4*)src;
                wa[p][1] = *(const float4*)(src + 4);
            }
        }
        #pragma unroll
        for (int kc = 0; kc < 2; ++kc) {
            short8 af[4], bfr[2];
            #pragma unroll
            for (int mi = 0; mi < 4; ++mi)
                af[mi] = *(const short8*)&Xs[buf][(wm + mi * 16 + lr) * 72 + kc * 32 + lk * 8];
            #pragma unroll
            for (int ni = 0; ni < 2; ++ni)
                bfr[ni] = *(const short8*)&Ws[buf][(wn + ni * 16 + lr) * 72 + kc * 32 + lk * 8];
            #pragma unroll
            for (int mi = 0; mi < 4; ++mi)
                #pragma unroll
                for (int ni = 0; ni < 2; ++ni)
                    acc[mi][ni] = __builtin_amdgcn_mfma_f32_16x16x32_bf16(af[mi], bfr[ni], acc[mi][ni], 0, 0, 0);
        }
        buf ^= 1;
    }
    #pragma unroll
    for (int mi = 0; mi < 4; ++mi)
        #pragma unroll
        for (int ni = 0; ni < 2; ++ni) {
            const int c = c0 + wn + ni * 16 + lr;
            const float bv2 = bc[c];
            #pragma unroll
            for (int i = 0; i < 4; ++i) {
                const int r = r0 + wm + mi * 16 + lk * 4 + i;
                H[(size_t)r * DIM + c] = f2bf(silu_f(acc[mi][ni][i] + bv2));
            }
        }
}

// ---------------- L2: kq (bf16) + act (f32 x, silu) co-scheduled -------------
// grid (132,4): bx<64 phik; bx 64..67 phiq (remapped); bx 68..131 act.
__global__ __launch_bounds__(256) void kq_act(
        const short* __restrict__ H, const short* __restrict__ WKB, const float* __restrict__ bk, short* __restrict__ PK,
        const short* __restrict__ WQB, const float* __restrict__ bq, short* __restrict__ PQ,
        const float* __restrict__ XF, const float* __restrict__ Waf, const float* __restrict__ ba,
        short* __restrict__ ACT) {
    __shared__ __align__(16) short Xs[2][128 * 72];
    __shared__ __align__(16) short Ws[2][64 * 72];
    const int bx = blockIdx.x;
    const int c0 = blockIdx.y * 64;
    const int tid = threadIdx.x;
    const int wv = tid >> 6, l = tid & 63;
    const int lr = l & 15, lk = l >> 4;
    const int wm = (wv >> 1) * 64, wn = (wv & 1) * 32;
    const int sr = tid >> 3, sc = (tid & 7) * 8;

    f32x4 acc[4][2];
    #pragma unroll
    for (int i = 0; i < 4; ++i)
        #pragma unroll
        for (int j = 0; j < 2; ++j) acc[i][j] = (f32x4){0.f, 0.f, 0.f, 0.f};

    if (bx >= 68) {  // ---- act path: f32 x @ Wa^T, silu ----
        const int r0 = (bx - 68) * 128;
        float4 xa[4][2], wa[2][2];
        #pragma unroll
        for (int p = 0; p < 4; ++p) {
            const float* src = XF + (size_t)(r0 + sr + p * 32) * DIM + sc;
            xa[p][0] = *(const float4*)src;
            xa[p][1] = *(const float4*)(src + 4);
        }
        #pragma unroll
        for (int p = 0; p < 2; ++p) {
            const float* src = Waf + (size_t)(c0 + sr + p * 32) * DIM + sc;
            wa[p][0] = *(const float4*)src;
            wa[p][1] = *(const float4*)(src + 4);
        }
        int buf = 0;
        for (int s = 0; s < 4; ++s) {
            #pragma unroll
            for (int p = 0; p < 4; ++p) {
                const int row = sr + p * 32;
                const float v[8] = {xa[p][0].x, xa[p][0].y, xa[p][0].z, xa[p][0].w,
                                    xa[p][1].x, xa[p][1].y, xa[p][1].z, xa[p][1].w};
                short8 sS;
                #pragma unroll
                for (int j = 0; j < 8; ++j) sS[j] = f2bf(v[j]);
                *(short8*)&Xs[buf][row * 72 + sc] = sS;
            }
            #pragma unroll
            for (int p = 0; p < 2; ++p) {
                const int row = sr + p * 32;
                const float v[8] = {wa[p][0].x, wa[p][0].y, wa[p][0].z, wa[p][0].w,
                                    wa[p][1].x, wa[p][1].y, wa[p][1].z, wa[p][1].w};
                short8 sS;
                #pragma unroll
                for (int j = 0; j < 8; ++j) sS[j] = f2bf(v[j]);
                *(short8*)&Ws[buf][row * 72 + sc] = sS;
            }
            __syncthreads();
            if (s < 3) {
                const int ktn = (s + 1) * 64;
                #pragma unroll
                for (int p = 0; p < 4; ++p) {
                    const float* src = XF + (size_t)(r0 + sr + p * 32) * DIM + ktn + sc;
                    xa[p][0] = *(const float4*)src;
                    xa[p][1] = *(const float4*)(src + 4);
                }
                #pragma unroll
                for (int p = 0; p < 2; ++p) {
                    const float* src = Waf + (size_t)(c0 + sr + p * 32) * DIM + ktn + sc;
                    wa[p][0] = *(const float4*)src;
                    wa[p][1] = *(const float4*)(src + 4);
                }
            }
            #pragma unroll
            for (int kc = 0; kc < 2; ++kc) {
                short8 af[4], bfr[2];
                #pragma unroll
                for (int mi = 0; mi < 4; ++mi)
                    af[mi] = *(const short8*)&Xs[buf][(wm + mi * 16 + lr) * 72 + kc * 32 + lk * 8];
                #pragma unroll
                for (int ni = 0; ni < 2; ++ni)
                    bfr[ni] = *(const short8*)&Ws[buf][(wn + ni * 16 + lr) * 72 + kc * 32 + lk * 8];
                #pragma unroll
                for (int mi = 0; mi < 4; ++mi)
                    #pragma unroll
                    for (int ni = 0; ni < 2; ++ni)
                        acc[mi][ni] = __builtin_amdgcn_mfma_f32_16x16x32_bf16(af[mi], bfr[ni], acc[mi][ni], 0, 0, 0);
            }
            buf ^= 1;
        }
        #pragma unroll
        for (int mi = 0; mi < 4; ++mi)
            #pragma unroll
            for (int ni = 0; ni < 2; ++ni) {
                const int c = c0 + wn + ni * 16 + lr;
                const float bv = ba[c];
                #pragma unroll
                for (int i = 0; i < 4; ++i) {
                    const int r = r0 + wm + mi * 16 + lk * 4 + i;
                    ACT[(size_t)r * DIM + c] = f2bf(silu_f(acc[mi][ni][i] + bv));
                }
            }
        return;
    }

    // ---- kq path: bf16 h @ W^T, elu2 ----
    const bool isq = bx >= 64;
    const short* W = isq ? WQB : WKB;
    const float* bias = isq ? bq : bk;
    short* Y = isq ? PQ : PK;
    const int r0 = (isq ? bx - 64 : bx) * 128;
    int growA[4];
    #pragma unroll
    for (int p = 0; p < 4; ++p) {
        int grow = r0 + sr + p * 32;
        if (isq) grow = ((grow >> 8) << 12) + (grow & 255);
        growA[p] = grow;
    }
    short8 xa[4], wa[2];
    #pragma unroll
    for (int p = 0; p < 4; ++p)
        xa[p] = *(const short8*)(H + (size_t)growA[p] * DIM + sc);
    #pragma unroll
    for (int p = 0; p < 2; ++p)
        wa[p] = *(const short8*)(W + (size_t)(c0 + sr + p * 32) * DIM + sc);
    int buf = 0;
    for (int s = 0; s < 4; ++s) {
        #pragma unroll
        for (int p = 0; p < 4; ++p)
            *(short8*)&Xs[buf][(sr + p * 32) * 72 + sc] = xa[p];
        #pragma unroll
        for (int p = 0; p < 2; ++p)
            *(short8*)&Ws[buf][(sr + p * 32) * 72 + sc] = wa[p];
        __syncthreads();
        if (s < 3) {
            const int ktn = (s + 1) * 64;
            #pragma unroll
            for (int p = 0; p < 4; ++p)
                xa[p] = *(const short8*)(H + (size_t)growA[p] * DIM + ktn + sc);
            #pragma unroll
            for (int p = 0; p < 2; ++p)
                wa[p] = *(const short8*)(W + (size_t)(c0 + sr + p * 32) * DIM + ktn + sc);
        }
        #pragma unroll
        for (int kc = 0; kc < 2; ++kc) {
            short8 af[4], bfr[2];
            #pragma unroll
            for (int mi = 0; mi < 4; ++mi)
                af[mi] = *(const short8*)&Xs[buf][(wm + mi * 16 + lr) * 72 + kc * 32 + lk * 8];
            #pragma unroll
            for (int ni = 0; ni < 2; ++ni)
                bfr[ni] = *(const short8*)&Ws[buf][(wn + ni * 16 + lr) * 72 + kc * 32 + lk * 8];
            #pragma unroll
            for (int mi = 0; mi < 4; ++mi)
                #pragma unroll
                for (int ni = 0; ni < 2; ++ni)
                    acc[mi][ni] = __builtin_amdgcn_mfma_f32_16x16x32_bf16(af[mi], bfr[ni], acc[mi][ni], 0, 0, 0);
        }
        buf ^= 1;
    }
    #pragma unroll
    for (int mi = 0; mi < 4; ++mi)
        #pragma unroll
        for (int ni = 0; ni < 2; ++ni) {
            const int c = c0 + wn + ni * 16 + lr;
            const float bv = bias[c];
            #pragma unroll
            for (int i = 0; i < 4; ++i) {
                const int r = r0 + wm + mi * 16 + lk * 4 + i;
                Y[(size_t)r * DIM + c] = f2bf(elu2_f(acc[mi][ni][i] + bv));
            }
        }
}

// ---------------- L3: KV double-buffered (pure) ------------------------------
__global__ __launch_bounds__(256) void kv_mfma(const short* __restrict__ HB, const short* __restrict__ PK,
                                               short* __restrict__ KVT) {
    __shared__ __align__(16) short Hs[2][64 * 68];
    __shared__ __align__(16) short Ps[2][64 * 68];
    const int tid = threadIdx.x;
    const int bm = blockIdx.x, b = bm >> 4, m = bm & 15;
    const int d0 = blockIdx.y * 64, c0 = blockIdx.z * 64;
    const int wv = tid >> 6, l = tid & 63;
    const int lr = l & 15, lk = l >> 4;
    const int wd = (wv >> 1) * 32, wc = (wv & 1) * 32;
    f32x4 acc[2][2];
    #pragma unroll
    for (int i = 0; i < 2; ++i)
        #pragma unroll
        for (int j = 0; j < 2; ++j) acc[i][j] = (f32x4){0.f, 0.f, 0.f, 0.f};
    const size_t hbase = (size_t)b * NTOK * DIM;
    const int sr = tid >> 3, sc = (tid & 7) * 8;

    short8 hv[2], pv[2];
    #pragma unroll
    for (int p = 0; p < 2; ++p) {
        const int w = sr + p * 32;
        const size_t gg = hbase + (size_t)(w * 16 + m) * DIM;
        hv[p] = *(const short8*)(HB + gg + d0 + sc);
        pv[p] = *(const short8*)(PK + gg + c0 + sc);
    }

    int buf = 0;
    for (int s = 0; s < 4; ++s) {
        #pragma unroll
        for (int p = 0; p < 2; ++p) {
            const int w = sr + p * 32;
            *(short4v*)&Hs[buf][w * 68 + sc]     = __builtin_shufflevector(hv[p], hv[p], 0, 1, 2, 3);
            *(short4v*)&Hs[buf][w * 68 + sc + 4] = __builtin_shufflevector(hv[p], hv[p], 4, 5, 6, 7);
            *(short4v*)&Ps[buf][w * 68 + sc]     = __builtin_shufflevector(pv[p], pv[p], 0, 1, 2, 3);
            *(short4v*)&Ps[buf][w * 68 + sc + 4] = __builtin_shufflevector(pv[p], pv[p], 4, 5, 6, 7);
        }
        __syncthreads();
        if (s < 3) {
            const int ktn = (s + 1) * 64;
            #pragma unroll
            for (int p = 0; p < 2; ++p) {
                const int w = sr + p * 32;
                const size_t gg = hbase + (size_t)((ktn + w) * 16 + m) * DIM;
                hv[p] = *(const short8*)(HB + gg + d0 + sc);
                pv[p] = *(const short8*)(PK + gg + c0 + sc);
            }
        }
        #pragma unroll
        for (int kc = 0; kc < 2; ++kc) {
            const int kb = kc * 32 + lk * 8;
            short8 af[2], bfr[2];
            #pragma unroll
            for (int di = 0; di < 2; ++di)
                #pragma unroll
                for (int i = 0; i < 8; ++i)
                    af[di][i] = Hs[buf][(kb + i) * 68 + wd + di * 16 + lr];
            #pragma unroll
            for (int ci = 0; ci < 2; ++ci)
                #pragma unroll
                for (int i = 0; i < 8; ++i)
                    bfr[ci][i] = Ps[buf][(kb + i) * 68 + wc + ci * 16 + lr];
            #pragma unroll
            for (int di = 0; di < 2; ++di)
                #pragma unroll
                for (int ci = 0; ci < 2; ++ci)
                    acc[di][ci] = __builtin_amdgcn_mfma_f32_16x16x32_bf16(af[di], bfr[ci], acc[di][ci], 0, 0, 0);
        }
        buf ^= 1;
    }
    #pragma unroll
    for (int di = 0; di < 2; ++di)
        #pragma unroll
        for (int ci = 0; ci < 2; ++ci)
            #pragma unroll
            for (int i = 0; i < 4; ++i) {
                const int d = d0 + wd + di * 16 + lk * 4 + i;
                const int c = c0 + wc + ci * 16 + lr;
                KVT[((size_t)bm * DIM + d) * DIM + c] = f2bf(acc[di][ci][i]);
            }
}

// ---------------- L4: attlin, Bs double-buffered (R17) -----------------------
__global__ __launch_bounds__(256) void attlin(
        const short* __restrict__ PQ, const short* __restrict__ KVT,
        const float* __restrict__ emb, const float* __restrict__ pw, const float* __restrict__ pb,
        const short* __restrict__ AR,
        const short* __restrict__ WLB, const float* __restrict__ bl,
        const short* __restrict__ HB, const float* __restrict__ G, const float* __restrict__ Bt,
        float* __restrict__ Y) {
    __shared__ __align__(16) short Qs[32 * 264];
    __shared__ __align__(16) short AGs[32 * 264];
    __shared__ __align__(16) short Bs[2][256 * 72];
    __shared__ float s1buf[32][2];
    __shared__ float s2buf[32][2];
    const int tid = threadIdx.x;
    const int wv = tid >> 6, l = tid & 63;
    const int lr = l & 15, lk = l >> 4;
    const int bm = blockIdx.x, b = bm >> 4, m = bm & 15;
    const int q0 = blockIdx.y * 32;
    const int wq = (wv >> 1) * 16;
    const int wd = (wv & 1) * 32;
    const int sr = tid >> 3, sc = (tid & 7) * 8;

    #pragma unroll
    for (int p = 0; p < 4; ++p) {
        const int chunk = tid + p * 256;
        const int row = chunk >> 5, cc = (chunk & 31) * 8;
        *(short8*)&Qs[row * 264 + cc] = *(const short8*)(PQ + (size_t)(b * 256 + q0 + row) * DIM + cc);
    }

    f32x4 accA[4][2];
    #pragma unroll
    for (int i = 0; i < 4; ++i)
        #pragma unroll
        for (int j = 0; j < 2; ++j) accA[i][j] = (f32x4){0.f, 0.f, 0.f, 0.f};
    short8 bv8[8];
    #pragma unroll
    for (int p = 0; p < 8; ++p)
        bv8[p] = *(const short8*)(KVT + ((size_t)bm * DIM + sr + p * 32) * DIM + sc);
    int buf = 0;
    for (int s = 0; s < 4; ++s) {
        const int kt = s * 64;
        #pragma unroll
        for (int p = 0; p < 8; ++p)
            *(short8*)&Bs[buf][(sr + p * 32) * 72 + sc] = bv8[p];
        __syncthreads();
        if (s < 3) {
            const int ktn = kt + 64;
            #pragma unroll
            for (int p = 0; p < 8; ++p)
                bv8[p] = *(const short8*)(KVT + ((size_t)bm * DIM + sr + p * 32) * DIM + ktn + sc);
        }
        #pragma unroll
        for (int kc = 0; kc < 2; ++kc) {
            const short8 af = *(const short8*)&Qs[(wq + lr) * 264 + kt + kc * 32 + lk * 8];
            #pragma unroll
            for (int dc = 0; dc < 4; ++dc)
                #pragma unroll
                for (int ni = 0; ni < 2; ++ni) {
                    const short8 bfr = *(const short8*)&Bs[buf][(dc * 64 + wd + ni * 16 + lr) * 72 + kc * 32 + lk * 8];
                    accA[dc][ni] = __builtin_amdgcn_mfma_f32_16x16x32_bf16(af, bfr, accA[dc][ni], 0, 0, 0);
                }
        }
        buf ^= 1;
    }
    __syncthreads();
    {
        const float pw0 = pw[0], pw1 = pw[1], pw2 = pw[2], pbv = pb[0];
        #pragma unroll
        for (int i = 0; i < 4; ++i) {
            const int rloc = wq + lk * 4 + i;
            const int qr = q0 + rloc;
            const int widx = qr >> 4, nidx = qr & 15;
            const float* e = emb + ((((size_t)(2 + b) * 256 + widx) * 16 + nidx) * 16 + m) * 3;
            const float pv = e[0] * pw0 + e[1] * pw1 + e[2] * pw2 + pbv;
            const int t = qr * 16 + m;
            #pragma unroll
            for (int dc = 0; dc < 4; ++dc)
                #pragma unroll
                for (int ni = 0; ni < 2; ++ni) {
                    const int d = dc * 64 + wd + ni * 16 + lr;
                    const size_t o = ((size_t)b * NTOK + t) * DIM + d;
                    AGs[rloc * 264 + d] = f2bf((accA[dc][ni][i] + pv) * bf2f(AR[o]));
                }
        }
    }
    __syncthreads();

    const int wn2 = (wv & 1) * 128;
    f32x4 accB[8];
    #pragma unroll
    for (int i = 0; i < 8; ++i) accB[i] = (f32x4){0.f, 0.f, 0.f, 0.f};
    #pragma unroll
    for (int p = 0; p < 8; ++p)
        bv8[p] = *(const short8*)(WLB + (size_t)(sr + p * 32) * DIM + sc);
    buf = 0;
    for (int s = 0; s < 4; ++s) {
        const int kt = s * 64;
        #pragma unroll
        for (int p = 0; p < 8; ++p)
            *(short8*)&Bs[buf][(sr + p * 32) * 72 + sc] = bv8[p];
        __syncthreads();
        if (s < 3) {
            const int ktn = kt + 64;
            #pragma unroll
            for (int p = 0; p < 8; ++p)
                bv8[p] = *(const short8*)(WLB + (size_t)(sr + p * 32) * DIM + ktn + sc);
        }
        #pragma unroll
        for (int kc = 0; kc < 2; ++kc) {
            const short8 af = *(const short8*)&AGs[(wq + lr) * 264 + kt + kc * 32 + lk * 8];
            #pragma unroll
            for (int ni = 0; ni < 8; ++ni) {
                const short8 bfr = *(const short8*)&Bs[buf][(wn2 + ni * 16 + lr) * 72 + kc * 32 + lk * 8];
                accB[ni] = __builtin_amdgcn_mfma_f32_16x16x32_bf16(af, bfr, accB[ni], 0, 0, 0);
            }
        }
        buf ^= 1;
    }
    float s1[4] = {0.f, 0.f, 0.f, 0.f}, s2[4] = {0.f, 0.f, 0.f, 0.f};
    #pragma unroll
    for (int ni = 0; ni < 8; ++ni) {
        const int col = wn2 + ni * 16 + lr;
        const float bv = bl[col];
        #pragma unroll
        for (int i = 0; i < 4; ++i) {
            const int rloc = wq + lk * 4 + i;
            const int t = (q0 + rloc) * 16 + m;
            const float z = accB[ni][i] + bv + bf2f(HB[((size_t)b * NTOK + t) * DIM + col]);
            accB[ni][i] = z;
            s1[i] += z; s2[i] += z * z;
        }
    }
    #pragma unroll
    for (int o = 1; o < 16; o <<= 1) {
        #pragma unroll
        for (int i = 0; i < 4; ++i) {
            s1[i] += __shfl_xor(s1[i], o);
            s2[i] += __shfl_xor(s2[i], o);
        }
    }
    if (lr == 0) {
        #pragma unroll
        for (int i = 0; i < 4; ++i) {
            const int rloc = wq + lk * 4 + i;
            s1buf[rloc][wv & 1] = s1[i];
            s2buf[rloc][wv & 1] = s2[i];
        }
    }
    __syncthreads();
    float mean[4], rstd[4];
    #pragma unroll
    for (int i = 0; i < 4; ++i) {
        const int rloc = wq + lk * 4 + i;
        const float t1 = s1buf[rloc][0] + s1buf[rloc][1];
        const float t2 = s2buf[rloc][0] + s2buf[rloc][1];
        const float mm = t1 * (1.f / DIM);
        mean[i] = mm;
        rstd[i] = rsqrtf(t2 * (1.f / DIM) - mm * mm + 1e-5f);
    }
    #pragma unroll
    for (int ni = 0; ni < 8; ++ni) {
        const int col = wn2 + ni * 16 + lr;
        const float gv = G[col], bv2 = Bt[col];
        #pragma unroll
        for (int i = 0; i < 4; ++i) {
            const int rloc = wq + lk * 4 + i;
            const int t = (q0 + rloc) * 16 + m;
            Y[((size_t)b * NTOK + t) * DIM + col] = (accB[ni][i] - mean[i]) * rstd[i] * gv + bv2;
        }
    }
}

extern "C" void kernel_launch(void* const* d_in, const int* in_sizes, int n_in,
                              void* d_out, int out_size, void* d_ws, size_t ws_size,
                              hipStream_t stream) {
    const float* x   = (const float*)d_in[0];
    const float* emb = (const float*)d_in[1];
    const float* Wa  = (const float*)d_in[2];
    const float* ba  = (const float*)d_in[3];
    const float* lng = (const float*)d_in[4];
    const float* lnb = (const float*)d_in[5];
    const float* Wc  = (const float*)d_in[6];
    const float* bc  = (const float*)d_in[7];
    const float* Wq  = (const float*)d_in[8];
    const float* bq  = (const float*)d_in[9];
    const float* Wk  = (const float*)d_in[10];
    const float* bk  = (const float*)d_in[11];
    const float* pw  = (const float*)d_in[12];
    const float* pb  = (const float*)d_in[13];
    const float* Wl  = (const float*)d_in[14];
    const float* bl  = (const float*)d_in[15];
    const float* ng  = (const float*)d_in[16];
    const float* nb  = (const float*)d_in[17];

    char* ws = (char*)d_ws;
    const size_t MB = 1024 * 1024;
    short* h_bf   = (short*)(ws + 0 * MB);    // 4 MB
    short* phik   = (short*)(ws + 4 * MB);    // 4 MB
    short* phiq   = (short*)(ws + 8 * MB);    // 256 KB
    short* kvT    = (short*)(ws + 9 * MB);    // 4 MB  [9,13)
    short* act_bf = (short*)(ws + 13 * MB);   // 4 MB  [13,17)
    short* Wk_bf  = (short*)(ws + 17 * MB);             // 128 KB
    short* Wq_bf  = (short*)(ws + 17 * MB + 128 * 1024);
    short* Wl_bf  = (short*)(ws + 17 * MB + 256 * 1024);

    gemm_h<<<dim3(88, 4), dim3(256), 0, stream>>>(x, Wc, bc, h_bf, lng, lnb,
                                                  Wk, Wk_bf, Wq, Wq_bf, Wl, Wl_bf);
    kq_act<<<dim3(132, 4), dim3(256), 0, stream>>>(h_bf, Wk_bf, bk, phik, Wq_bf, bq, phiq,
                                                   x, Wa, ba, act_bf);
    kv_mfma<<<dim3(32, 4, 4), dim3(256), 0, stream>>>(h_bf, phik, kvT);
    attlin<<<dim3(32, 8), dim3(256), 0, stream>>>(phiq, kvT, emb, pw, pb, act_bf, Wl_bf, bl,
                                                  h_bf, ng, nb, (float*)d_out);
}

// Round 19
// 53.553 us; speedup vs baseline: 1.0345x; 1.0345x over previous
//
#include <hip/hip_runtime.h>

// MSMLTransformerLayer — R17 restore (best: 53.2 µs). 4 launches:
// fused_dual (act+h, dbuf+prefetch, Wk/Wq casts) -> gemm_kq (dbuf) ->
// kv_mfma (dbuf, +Wl cast) -> attlin (Bs dbuf). R18 DAG-repack (55.4),
// R13 recompute (58.7), R14 full-K (66.1), R12 coop (398) all falsified.

#define DIM 256
#define NTOK 4096

typedef __attribute__((ext_vector_type(8))) short short8;
typedef __attribute__((ext_vector_type(4))) short short4v;
typedef __attribute__((ext_vector_type(4))) float f32x4;

__device__ __forceinline__ float silu_f(float z) { return z / (1.f + __expf(-z)); }
__device__ __forceinline__ float elu2_f(float z) { return z > 0.f ? z + 2.f : __expf(z) + 1.f; }

__device__ __forceinline__ short f2bf(float f) {
    union { float f; unsigned u; } v; v.f = f;
    unsigned r = v.u + 0x7fffu + ((v.u >> 16) & 1u);
    return (short)(r >> 16);
}
__device__ __forceinline__ float bf2f(short s) {
    union { unsigned u; float f; } v; v.u = ((unsigned)(unsigned short)s) << 16;
    return v.f;
}
__device__ __forceinline__ short8 cvt8(const float* src) {
    const float4 a = *(const float4*)src;
    const float4 c = *(const float4*)(src + 4);
    short8 s;
    s[0] = f2bf(a.x); s[1] = f2bf(a.y); s[2] = f2bf(a.z); s[3] = f2bf(a.w);
    s[4] = f2bf(c.x); s[5] = f2bf(c.y); s[6] = f2bf(c.z); s[7] = f2bf(c.w);
    return s;
}
__device__ __forceinline__ void cast_chunk(const float* __restrict__ src, short* __restrict__ dst,
                                           int chunk, int tid) {
    const int base = chunk * 8192 + tid * 32;
    #pragma unroll
    for (int j = 0; j < 4; ++j)
        *(short8*)(dst + base + j * 8) = cvt8(src + base + j * 8);
}

// ---------------- fused dual GEMM (silu), double-buffered --------------------
__global__ __launch_bounds__(256) void fused_dual(
        const float* __restrict__ XF,
        const float* __restrict__ W0f, const float* __restrict__ b0, short* __restrict__ Y0,
        const float* __restrict__ W1f, const float* __restrict__ b1, short* __restrict__ Y1,
        const float* __restrict__ G, const float* __restrict__ Bt,
        const float* __restrict__ Wkf, short* __restrict__ WKB,
        const float* __restrict__ Wqf, short* __restrict__ WQB) {
    const int tid = threadIdx.x;
    if (blockIdx.x >= 64) {
        if (blockIdx.y == 0 && blockIdx.z == 0) {
            const int which = blockIdx.x - 64;
            if (which < 8) cast_chunk(Wkf, WKB, which, tid);
            else cast_chunk(Wqf, WQB, which - 8, tid);
        }
        return;
    }
    __shared__ __align__(16) short Xs[2][128 * 72];
    __shared__ __align__(16) short Ws[2][64 * 72];
    __shared__ float stats[128][2];
    const int zz = blockIdx.z;
    const float* Wf = zz ? W1f : W0f;
    const float* bias = zz ? b1 : b0;
    short* Y = zz ? Y1 : Y0;
    const int wv = tid >> 6, l = tid & 63;
    const int lr = l & 15, lk = l >> 4;
    const int r0 = blockIdx.x * 128, c0 = blockIdx.y * 64;
    const int wm = (wv >> 1) * 64, wn = (wv & 1) * 32;
    const int sr = tid >> 3, sc = (tid & 7) * 8;

    if (zz) {
        const int prow = tid >> 1, phalf = tid & 1;
        const float* src = XF + (size_t)(r0 + prow) * DIM + phalf * 128;
        float a1 = 0.f, a2 = 0.f;
        #pragma unroll 8
        for (int j = 0; j < 32; ++j) {
            const float4 v = *(const float4*)(src + j * 4);
            a1 += v.x + v.y + v.z + v.w;
            a2 += v.x * v.x + v.y * v.y + v.z * v.z + v.w * v.w;
        }
        a1 += __shfl_xor(a1, 1);
        a2 += __shfl_xor(a2, 1);
        if (!phalf) {
            const float mm = a1 * (1.f / DIM);
            stats[prow][0] = mm;
            stats[prow][1] = rsqrtf(a2 * (1.f / DIM) - mm * mm + 1e-5f);
        }
        __syncthreads();
    }

    f32x4 acc[4][2];
    #pragma unroll
    for (int i = 0; i < 4; ++i)
        #pragma unroll
        for (int j = 0; j < 2; ++j) acc[i][j] = (f32x4){0.f, 0.f, 0.f, 0.f};

    float4 xa[4][2], wa[2][2];
    #pragma unroll
    for (int p = 0; p < 4; ++p) {
        const float* src = XF + (size_t)(r0 + sr + p * 32) * DIM + sc;
        xa[p][0] = *(const float4*)src;
        xa[p][1] = *(const float4*)(src + 4);
    }
    #pragma unroll
    for (int p = 0; p < 2; ++p) {
        const float* src = Wf + (size_t)(c0 + sr + p * 32) * DIM + sc;
        wa[p][0] = *(const float4*)src;
        wa[p][1] = *(const float4*)(src + 4);
    }

    int buf = 0;
    for (int s = 0; s < 4; ++s) {
        const int kt = s * 64;
        if (zz) {
            const float4 g1 = *(const float4*)(G + kt + sc);
            const float4 g2 = *(const float4*)(G + kt + sc + 4);
            const float4 t1 = *(const float4*)(Bt + kt + sc);
            const float4 t2 = *(const float4*)(Bt + kt + sc + 4);
            const float gv[8] = {g1.x, g1.y, g1.z, g1.w, g2.x, g2.y, g2.z, g2.w};
            const float bv[8] = {t1.x, t1.y, t1.z, t1.w, t2.x, t2.y, t2.z, t2.w};
            #pragma unroll
            for (int p = 0; p < 4; ++p) {
                const int row = sr + p * 32;
                const float mm = stats[row][0], rs = stats[row][1];
                const float v[8] = {xa[p][0].x, xa[p][0].y, xa[p][0].z, xa[p][0].w,
                                    xa[p][1].x, xa[p][1].y, xa[p][1].z, xa[p][1].w};
                short8 sS;
                #pragma unroll
                for (int j = 0; j < 8; ++j) sS[j] = f2bf((v[j] - mm) * rs * gv[j] + bv[j]);
                *(short8*)&Xs[buf][row * 72 + sc] = sS;
            }
        } else {
            #pragma unroll
            for (int p = 0; p < 4; ++p) {
                const int row = sr + p * 32;
                const float v[8] = {xa[p][0].x, xa[p][0].y, xa[p][0].z, xa[p][0].w,
                                    xa[p][1].x, xa[p][1].y, xa[p][1].z, xa[p][1].w};
                short8 sS;
                #pragma unroll
                for (int j = 0; j < 8; ++j) sS[j] = f2bf(v[j]);
                *(short8*)&Xs[buf][row * 72 + sc] = sS;
            }
        }
        #pragma unroll
        for (int p = 0; p < 2; ++p) {
            const int row = sr + p * 32;
            const float v[8] = {wa[p][0].x, wa[p][0].y, wa[p][0].z, wa[p][0].w,
                                wa[p][1].x, wa[p][1].y, wa[p][1].z, wa[p][1].w};
            short8 sS;
            #pragma unroll
            for (int j = 0; j < 8; ++j) sS[j] = f2bf(v[j]);
            *(short8*)&Ws[buf][row * 72 + sc] = sS;
        }
        __syncthreads();
        if (s < 3) {
            const int ktn = kt + 64;
            #pragma unroll
            for (int p = 0; p < 4; ++p) {
                const float* src = XF + (size_t)(r0 + sr + p * 32) * DIM + ktn + sc;
                xa[p][0] = *(const float4*)src;
                xa[p][1] = *(const float4*)(src + 4);
            }
            #pragma unroll
            for (int p = 0; p < 2; ++p) {
                const float* src = Wf + (size_t)(c0 + sr + p * 32) * DIM + ktn + sc;
                wa[p][0] = *(const float4*)src;
                wa[p][1] = *(const float4*)(src + 4);
            }
        }
        #pragma unroll
        for (int kc = 0; kc < 2; ++kc) {
            short8 af[4], bfr[2];
            #pragma unroll
            for (int mi = 0; mi < 4; ++mi)
                af[mi] = *(const short8*)&Xs[buf][(wm + mi * 16 + lr) * 72 + kc * 32 + lk * 8];
            #pragma unroll
            for (int ni = 0; ni < 2; ++ni)
                bfr[ni] = *(const short8*)&Ws[buf][(wn + ni * 16 + lr) * 72 + kc * 32 + lk * 8];
            #pragma unroll
            for (int mi = 0; mi < 4; ++mi)
                #pragma unroll
                for (int ni = 0; ni < 2; ++ni)
                    acc[mi][ni] = __builtin_amdgcn_mfma_f32_16x16x32_bf16(af[mi], bfr[ni], acc[mi][ni], 0, 0, 0);
        }
        buf ^= 1;
    }
    #pragma unroll
    for (int mi = 0; mi < 4; ++mi)
        #pragma unroll
        for (int ni = 0; ni < 2; ++ni) {
            const int c = c0 + wn + ni * 16 + lr;
            const float bv2 = bias[c];
            #pragma unroll
            for (int i = 0; i < 4; ++i) {
                const int r = r0 + wm + mi * 16 + lk * 4 + i;
                Y[(size_t)r * DIM + c] = f2bf(silu_f(acc[mi][ni][i] + bv2));
            }
        }
}

// ---------------- k/q GEMM (elu+2), double-buffered, bf16 weights ------------
__global__ __launch_bounds__(256) void gemm_kq(
        const short* __restrict__ H, const short* __restrict__ WKB, const float* __restrict__ bk, short* __restrict__ PK,
        const short* __restrict__ WQB, const float* __restrict__ bq, short* __restrict__ PQ) {
    __shared__ __align__(16) short Xs[2][128 * 72];
    __shared__ __align__(16) short Ws[2][64 * 72];
    const int bx = blockIdx.x;
    const bool isq = bx >= 64;
    const short* W = isq ? WQB : WKB;
    const float* bias = isq ? bq : bk;
    short* Y = isq ? PQ : PK;
    const int r0 = (isq ? bx - 64 : bx) * 128;
    const int c0 = blockIdx.y * 64;
    const int tid = threadIdx.x;
    const int wv = tid >> 6, l = tid & 63;
    const int lr = l & 15, lk = l >> 4;
    const int wm = (wv >> 1) * 64, wn = (wv & 1) * 32;
    const int sr = tid >> 3, sc = (tid & 7) * 8;

    int growA[4];
    #pragma unroll
    for (int p = 0; p < 4; ++p) {
        int grow = r0 + sr + p * 32;
        if (isq) grow = ((grow >> 8) << 12) + (grow & 255);
        growA[p] = grow;
    }

    f32x4 acc[4][2];
    #pragma unroll
    for (int i = 0; i < 4; ++i)
        #pragma unroll
        for (int j = 0; j < 2; ++j) acc[i][j] = (f32x4){0.f, 0.f, 0.f, 0.f};

    short8 xa[4], wa[2];
    #pragma unroll
    for (int p = 0; p < 4; ++p)
        xa[p] = *(const short8*)(H + (size_t)growA[p] * DIM + sc);
    #pragma unroll
    for (int p = 0; p < 2; ++p)
        wa[p] = *(const short8*)(W + (size_t)(c0 + sr + p * 32) * DIM + sc);

    int buf = 0;
    for (int s = 0; s < 4; ++s) {
        #pragma unroll
        for (int p = 0; p < 4; ++p)
            *(short8*)&Xs[buf][(sr + p * 32) * 72 + sc] = xa[p];
        #pragma unroll
        for (int p = 0; p < 2; ++p)
            *(short8*)&Ws[buf][(sr + p * 32) * 72 + sc] = wa[p];
        __syncthreads();
        if (s < 3) {
            const int ktn = (s + 1) * 64;
            #pragma unroll
            for (int p = 0; p < 4; ++p)
                xa[p] = *(const short8*)(H + (size_t)growA[p] * DIM + ktn + sc);
            #pragma unroll
            for (int p = 0; p < 2; ++p)
                wa[p] = *(const short8*)(W + (size_t)(c0 + sr + p * 32) * DIM + ktn + sc);
        }
        #pragma unroll
        for (int kc = 0; kc < 2; ++kc) {
            short8 af[4], bfr[2];
            #pragma unroll
            for (int mi = 0; mi < 4; ++mi)
                af[mi] = *(const short8*)&Xs[buf][(wm + mi * 16 + lr) * 72 + kc * 32 + lk * 8];
            #pragma unroll
            for (int ni = 0; ni < 2; ++ni)
                bfr[ni] = *(const short8*)&Ws[buf][(wn + ni * 16 + lr) * 72 + kc * 32 + lk * 8];
            #pragma unroll
            for (int mi = 0; mi < 4; ++mi)
                #pragma unroll
                for (int ni = 0; ni < 2; ++ni)
                    acc[mi][ni] = __builtin_amdgcn_mfma_f32_16x16x32_bf16(af[mi], bfr[ni], acc[mi][ni], 0, 0, 0);
        }
        buf ^= 1;
    }
    #pragma unroll
    for (int mi = 0; mi < 4; ++mi)
        #pragma unroll
        for (int ni = 0; ni < 2; ++ni) {
            const int c = c0 + wn + ni * 16 + lr;
            const float bv = bias[c];
            #pragma unroll
            for (int i = 0; i < 4; ++i) {
                const int r = r0 + wm + mi * 16 + lk * 4 + i;
                Y[(size_t)r * DIM + c] = f2bf(elu2_f(acc[mi][ni][i] + bv));
            }
        }
}

// ---------------- KV double-buffered + Wl cast side-blocks -------------------
__global__ __launch_bounds__(256) void kv_mfma(const short* __restrict__ HB, const short* __restrict__ PK,
                                               short* __restrict__ KVT,
                                               const float* __restrict__ Wlf, short* __restrict__ WLB) {
    const int tid = threadIdx.x;
    if (blockIdx.x >= 32) {
        if (blockIdx.y == 0 && blockIdx.z == 0)
            cast_chunk(Wlf, WLB, blockIdx.x - 32, tid);
        return;
    }
    __shared__ __align__(16) short Hs[2][64 * 68];
    __shared__ __align__(16) short Ps[2][64 * 68];
    const int bm = blockIdx.x, b = bm >> 4, m = bm & 15;
    const int d0 = blockIdx.y * 64, c0 = blockIdx.z * 64;
    const int wv = tid >> 6, l = tid & 63;
    const int lr = l & 15, lk = l >> 4;
    const int wd = (wv >> 1) * 32, wc = (wv & 1) * 32;
    f32x4 acc[2][2];
    #pragma unroll
    for (int i = 0; i < 2; ++i)
        #pragma unroll
        for (int j = 0; j < 2; ++j) acc[i][j] = (f32x4){0.f, 0.f, 0.f, 0.f};
    const size_t hbase = (size_t)b * NTOK * DIM;
    const int sr = tid >> 3, sc = (tid & 7) * 8;

    short8 hv[2], pv[2];
    #pragma unroll
    for (int p = 0; p < 2; ++p) {
        const int w = sr + p * 32;
        const size_t gg = hbase + (size_t)(w * 16 + m) * DIM;
        hv[p] = *(const short8*)(HB + gg + d0 + sc);
        pv[p] = *(const short8*)(PK + gg + c0 + sc);
    }

    int buf = 0;
    for (int s = 0; s < 4; ++s) {
        #pragma unroll
        for (int p = 0; p < 2; ++p) {
            const int w = sr + p * 32;
            *(short4v*)&Hs[buf][w * 68 + sc]     = __builtin_shufflevector(hv[p], hv[p], 0, 1, 2, 3);
            *(short4v*)&Hs[buf][w * 68 + sc + 4] = __builtin_shufflevector(hv[p], hv[p], 4, 5, 6, 7);
            *(short4v*)&Ps[buf][w * 68 + sc]     = __builtin_shufflevector(pv[p], pv[p], 0, 1, 2, 3);
            *(short4v*)&Ps[buf][w * 68 + sc + 4] = __builtin_shufflevector(pv[p], pv[p], 4, 5, 6, 7);
        }
        __syncthreads();
        if (s < 3) {
            const int ktn = (s + 1) * 64;
            #pragma unroll
            for (int p = 0; p < 2; ++p) {
                const int w = sr + p * 32;
                const size_t gg = hbase + (size_t)((ktn + w) * 16 + m) * DIM;
                hv[p] = *(const short8*)(HB + gg + d0 + sc);
                pv[p] = *(const short8*)(PK + gg + c0 + sc);
            }
        }
        #pragma unroll
        for (int kc = 0; kc < 2; ++kc) {
            const int kb = kc * 32 + lk * 8;
            short8 af[2], bfr[2];
            #pragma unroll
            for (int di = 0; di < 2; ++di)
                #pragma unroll
                for (int i = 0; i < 8; ++i)
                    af[di][i] = Hs[buf][(kb + i) * 68 + wd + di * 16 + lr];
            #pragma unroll
            for (int ci = 0; ci < 2; ++ci)
                #pragma unroll
                for (int i = 0; i < 8; ++i)
                    bfr[ci][i] = Ps[buf][(kb + i) * 68 + wc + ci * 16 + lr];
            #pragma unroll
            for (int di = 0; di < 2; ++di)
                #pragma unroll
                for (int ci = 0; ci < 2; ++ci)
                    acc[di][ci] = __builtin_amdgcn_mfma_f32_16x16x32_bf16(af[di], bfr[ci], acc[di][ci], 0, 0, 0);
        }
        buf ^= 1;
    }
    #pragma unroll
    for (int di = 0; di < 2; ++di)
        #pragma unroll
        for (int ci = 0; ci < 2; ++ci)
            #pragma unroll
            for (int i = 0; i < 4; ++i) {
                const int d = d0 + wd + di * 16 + lk * 4 + i;
                const int c = c0 + wc + ci * 16 + lr;
                KVT[((size_t)bm * DIM + d) * DIM + c] = f2bf(acc[di][ci][i]);
            }
}

// ---------------- attlin: Bs double-buffered ---------------------------------
__global__ __launch_bounds__(256) void attlin(
        const short* __restrict__ PQ, const short* __restrict__ KVT,
        const float* __restrict__ emb, const float* __restrict__ pw, const float* __restrict__ pb,
        const short* __restrict__ AR,
        const short* __restrict__ WLB, const float* __restrict__ bl,
        const short* __restrict__ HB, const float* __restrict__ G, const float* __restrict__ Bt,
        float* __restrict__ Y) {
    __shared__ __align__(16) short Qs[32 * 264];
    __shared__ __align__(16) short AGs[32 * 264];
    __shared__ __align__(16) short Bs[2][256 * 72];
    __shared__ float s1buf[32][2];
    __shared__ float s2buf[32][2];
    const int tid = threadIdx.x;
    const int wv = tid >> 6, l = tid & 63;
    const int lr = l & 15, lk = l >> 4;
    const int bm = blockIdx.x, b = bm >> 4, m = bm & 15;
    const int q0 = blockIdx.y * 32;
    const int wq = (wv >> 1) * 16;
    const int wd = (wv & 1) * 32;
    const int sr = tid >> 3, sc = (tid & 7) * 8;

    #pragma unroll
    for (int p = 0; p < 4; ++p) {
        const int chunk = tid + p * 256;
        const int row = chunk >> 5, cc = (chunk & 31) * 8;
        *(short8*)&Qs[row * 264 + cc] = *(const short8*)(PQ + (size_t)(b * 256 + q0 + row) * DIM + cc);
    }

    f32x4 accA[4][2];
    #pragma unroll
    for (int i = 0; i < 4; ++i)
        #pragma unroll
        for (int j = 0; j < 2; ++j) accA[i][j] = (f32x4){0.f, 0.f, 0.f, 0.f};
    short8 bv8[8];
    #pragma unroll
    for (int p = 0; p < 8; ++p)
        bv8[p] = *(const short8*)(KVT + ((size_t)bm * DIM + sr + p * 32) * DIM + sc);
    int buf = 0;
    for (int s = 0; s < 4; ++s) {
        const int kt = s * 64;
        #pragma unroll
        for (int p = 0; p < 8; ++p)
            *(short8*)&Bs[buf][(sr + p * 32) * 72 + sc] = bv8[p];
        __syncthreads();
        if (s < 3) {
            const int ktn = kt + 64;
            #pragma unroll
            for (int p = 0; p < 8; ++p)
                bv8[p] = *(const short8*)(KVT + ((size_t)bm * DIM + sr + p * 32) * DIM + ktn + sc);
        }
        #pragma unroll
        for (int kc = 0; kc < 2; ++kc) {
            const short8 af = *(const short8*)&Qs[(wq + lr) * 264 + kt + kc * 32 + lk * 8];
            #pragma unroll
            for (int dc = 0; dc < 4; ++dc)
                #pragma unroll
                for (int ni = 0; ni < 2; ++ni) {
                    const short8 bfr = *(const short8*)&Bs[buf][(dc * 64 + wd + ni * 16 + lr) * 72 + kc * 32 + lk * 8];
                    accA[dc][ni] = __builtin_amdgcn_mfma_f32_16x16x32_bf16(af, bfr, accA[dc][ni], 0, 0, 0);
                }
        }
        buf ^= 1;
    }
    __syncthreads();
    {
        const float pw0 = pw[0], pw1 = pw[1], pw2 = pw[2], pbv = pb[0];
        #pragma unroll
        for (int i = 0; i < 4; ++i) {
            const int rloc = wq + lk * 4 + i;
            const int qr = q0 + rloc;
            const int widx = qr >> 4, nidx = qr & 15;
            const float* e = emb + ((((size_t)(2 + b) * 256 + widx) * 16 + nidx) * 16 + m) * 3;
            const float pv = e[0] * pw0 + e[1] * pw1 + e[2] * pw2 + pbv;
            const int t = qr * 16 + m;
            #pragma unroll
            for (int dc = 0; dc < 4; ++dc)
                #pragma unroll
                for (int ni = 0; ni < 2; ++ni) {
                    const int d = dc * 64 + wd + ni * 16 + lr;
                    const size_t o = ((size_t)b * NTOK + t) * DIM + d;
                    AGs[rloc * 264 + d] = f2bf((accA[dc][ni][i] + pv) * bf2f(AR[o]));
                }
        }
    }
    __syncthreads();

    const int wn2 = (wv & 1) * 128;
    f32x4 accB[8];
    #pragma unroll
    for (int i = 0; i < 8; ++i) accB[i] = (f32x4){0.f, 0.f, 0.f, 0.f};
    #pragma unroll
    for (int p = 0; p < 8; ++p)
        bv8[p] = *(const short8*)(WLB + (size_t)(sr + p * 32) * DIM + sc);
    buf = 0;
    for (int s = 0; s < 4; ++s) {
        const int kt = s * 64;
        #pragma unroll
        for (int p = 0; p < 8; ++p)
            *(short8*)&Bs[buf][(sr + p * 32) * 72 + sc] = bv8[p];
        __syncthreads();
        if (s < 3) {
            const int ktn = kt + 64;
            #pragma unroll
            for (int p = 0; p < 8; ++p)
                bv8[p] = *(const short8*)(WLB + (size_t)(sr + p * 32) * DIM + ktn + sc);
        }
        #pragma unroll
        for (int kc = 0; kc < 2; ++kc) {
            const short8 af = *(const short8*)&AGs[(wq + lr) * 264 + kt + kc * 32 + lk * 8];
            #pragma unroll
            for (int ni = 0; ni < 8; ++ni) {
                const short8 bfr = *(const short8*)&Bs[buf][(wn2 + ni * 16 + lr) * 72 + kc * 32 + lk * 8];
                accB[ni] = __builtin_amdgcn_mfma_f32_16x16x32_bf16(af, bfr, accB[ni], 0, 0, 0);
            }
        }
        buf ^= 1;
    }
    float s1[4] = {0.f, 0.f, 0.f, 0.f}, s2[4] = {0.f, 0.f, 0.f, 0.f};
    #pragma unroll
    for (int ni = 0; ni < 8; ++ni) {
        const int col = wn2 + ni * 16 + lr;
        const float bv = bl[col];
        #pragma unroll
        for (int i = 0; i < 4; ++i) {
            const int rloc = wq + lk * 4 + i;
            const int t = (q0 + rloc) * 16 + m;
            const float z = accB[ni][i] + bv + bf2f(HB[((size_t)b * NTOK + t) * DIM + col]);
            accB[ni][i] = z;
            s1[i] += z; s2[i] += z * z;
        }
    }
    #pragma unroll
    for (int o = 1; o < 16; o <<= 1) {
        #pragma unroll
        for (int i = 0; i < 4; ++i) {
            s1[i] += __shfl_xor(s1[i], o);
            s2[i] += __shfl_xor(s2[i], o);
        }
    }
    if (lr == 0) {
        #pragma unroll
        for (int i = 0; i < 4; ++i) {
            const int rloc = wq + lk * 4 + i;
            s1buf[rloc][wv & 1] = s1[i];
            s2buf[rloc][wv & 1] = s2[i];
        }
    }
    __syncthreads();
    float mean[4], rstd[4];
    #pragma unroll
    for (int i = 0; i < 4; ++i) {
        const int rloc = wq + lk * 4 + i;
        const float t1 = s1buf[rloc][0] + s1buf[rloc][1];
        const float t2 = s2buf[rloc][0] + s2buf[rloc][1];
        const float mm = t1 * (1.f / DIM);
        mean[i] = mm;
        rstd[i] = rsqrtf(t2 * (1.f / DIM) - mm * mm + 1e-5f);
    }
    #pragma unroll
    for (int ni = 0; ni < 8; ++ni) {
        const int col = wn2 + ni * 16 + lr;
        const float gv = G[col], bv2 = Bt[col];
        #pragma unroll
        for (int i = 0; i < 4; ++i) {
            const int rloc = wq + lk * 4 + i;
            const int t = (q0 + rloc) * 16 + m;
            Y[((size_t)b * NTOK + t) * DIM + col] = (accB[ni][i] - mean[i]) * rstd[i] * gv + bv2;
        }
    }
}

extern "C" void kernel_launch(void* const* d_in, const int* in_sizes, int n_in,
                              void* d_out, int out_size, void* d_ws, size_t ws_size,
                              hipStream_t stream) {
    const float* x   = (const float*)d_in[0];
    const float* emb = (const float*)d_in[1];
    const float* Wa  = (const float*)d_in[2];
    const float* ba  = (const float*)d_in[3];
    const float* lng = (const float*)d_in[4];
    const float* lnb = (const float*)d_in[5];
    const float* Wc  = (const float*)d_in[6];
    const float* bc  = (const float*)d_in[7];
    const float* Wq  = (const float*)d_in[8];
    const float* bq  = (const float*)d_in[9];
    const float* Wk  = (const float*)d_in[10];
    const float* bk  = (const float*)d_in[11];
    const float* pw  = (const float*)d_in[12];
    const float* pb  = (const float*)d_in[13];
    const float* Wl  = (const float*)d_in[14];
    const float* bl  = (const float*)d_in[15];
    const float* ng  = (const float*)d_in[16];
    const float* nb  = (const float*)d_in[17];

    char* ws = (char*)d_ws;
    const size_t MB = 1024 * 1024;
    short* h_bf   = (short*)(ws + 0 * MB);    // 4 MB
    short* phik   = (short*)(ws + 4 * MB);    // 4 MB
    short* phiq   = (short*)(ws + 8 * MB);    // 256 KB
    short* kvT    = (short*)(ws + 9 * MB);    // 4 MB  [9,13)
    short* act_bf = (short*)(ws + 13 * MB);   // 4 MB  [13,17)
    short* Wk_bf  = (short*)(ws + 17 * MB);             // 128 KB
    short* Wq_bf  = (short*)(ws + 17 * MB + 128 * 1024);
    short* Wl_bf  = (short*)(ws + 17 * MB + 256 * 1024);

    fused_dual<<<dim3(80, 4, 2), dim3(256), 0, stream>>>(x, Wa, ba, act_bf,
                                                         Wc, bc, h_bf, lng, lnb,
                                                         Wk, Wk_bf, Wq, Wq_bf);
    gemm_kq<<<dim3(68, 4), dim3(256), 0, stream>>>(h_bf, Wk_bf, bk, phik, Wq_bf, bq, phiq);
    kv_mfma<<<dim3(40, 4, 4), dim3(256), 0, stream>>>(h_bf, phik, kvT, Wl, Wl_bf);
    attlin<<<dim3(32, 8), dim3(256), 0, stream>>>(phiq, kvT, emb, pw, pb, act_bf, Wl_bf, bl,
                                                  h_bf, ng, nb, (float*)d_out);
}